// Round 13
// baseline (209.929 us; speedup 1.0000x reference)
//
#include <hip/hip_runtime.h>

// Problem constants (fixed by setup_inputs)
#define B_  32
#define H_  512
#define W_  512
#define NX_ 1024
#define NY_ 1024

// Grouped-halo staged row: 8 groups x (64 data + 4 halo floats) = 544 floats.
// Window [c0,c0+3] contiguous at off = c0 + 4*(c0>>6) (precomputed in bx0).
// Linear in f4 slots (17/group) -> global_load_lds keeps a linear LDS dst;
// the halo lives in the per-lane SOURCE address (idx = min(16g+sub,127)).
#define SLOT_G  17
#define SLOTS_R 136          // f4 slots per staged row
#define SROW    544          // floats per staged row
#define NROWS   4            // rows staged per block (one y-window)
#define NSLOT   (NROWS * SLOTS_R)   // 544 slots = 8704 B

__device__ __forceinline__ float4 f4fma(float s, float4 a, float4 acc) {
    acc.x += s * a.x; acc.y += s * a.y; acc.z += s * a.z; acc.w += s * a.w;
    return acc;
}

__device__ __forceinline__ void gload_lds16(const float* g, float* l) {
    __builtin_amdgcn_global_load_lds(
        (const __attribute__((address_space(1))) void*)g,
        (__attribute__((address_space(3))) void*)l,
        16, 0, 0);
}

// Hermite basis + FD tangents folded into a contiguous 4-tap window
// [c0, c0+3]; boundary cases pre-shifted, out-of-range taps weight-0.
__device__ __forceinline__ void hermite_window(float x, int N, int& c0, float4& v) {
    int i = (int)floorf(x);
    i = min(max(i, 0), N - 2);
    float t  = x - (float)i;
    float t2 = t * t;
    float t3 = t2 * t;
    float h00 = 1.0f - 3.0f * t2 + 2.0f * t3;
    float h10 = t - 2.0f * t2 + t3;
    float h01 = 3.0f * t2 - 2.0f * t3;
    float h11 = t3 - t2;
    if (i == 0) {
        c0 = 0;
        v = make_float4(h00 - h10 - 0.5f * h11, h01 + h10, 0.5f * h11, 0.0f);
    } else if (i == N - 2) {
        c0 = i - 1;
        v = make_float4(-0.5f * h10, h00 - h11, h01 + 0.5f * h10 + h11, 0.0f);
    } else {
        c0 = i - 1;
        v = make_float4(-0.5f * h10, h00 - 0.5f * h11, h01 + 0.5f * h10, 0.5f * h11);
    }
}

// Precompute query tables: x windows (grouped-halo offset) + y windows (row).
__global__ void prep_tables(const float* __restrict__ xs, const float* __restrict__ ys,
                            float4* __restrict__ wxw, int* __restrict__ bx0,
                            float4* __restrict__ wyw, int* __restrict__ ry0) {
    int q = blockIdx.x * blockDim.x + threadIdx.x;
    if (q < NX_) {
        int c; float4 w;
        hermite_window(xs[q], W_, c, w);
        wxw[q] = w;
        bx0[q] = c + ((c >> 6) << 2);       // grouped-halo LDS offset
    } else if (q < NX_ + NY_) {
        int qq = q - NX_;
        int c; float4 w;
        hermite_window(ys[qq], H_, c, w);
        wyw[qq] = w;
        ry0[qq] = c;                        // first source row of the window
    }
}

// Row-per-block streaming stencil. One block = one output row (qy) x batch.
//   - stage the 4 source rows [ry, ry+3] (row-clamped) into grouped-halo LDS
//   - each thread col-interps its 4 qx over the 4 rows (64 fma)
//   - combine with WAVE-UNIFORM y-weights (4 fma) -- no tables, no switch
//   - store one full 4KB row: every 128B line written wholly by one
//     instruction of one wave (fillBuffer pattern -> 1.0x writes)
// 32768 tiny blocks; TLP (32 waves/CU) hides all latencies.
__global__ __launch_bounds__(256) void fused(
    const float* __restrict__ sig,
    const float4* __restrict__ wxw, const int* __restrict__ bx0,
    const float4* __restrict__ wyw, const int* __restrict__ ry0,
    float* __restrict__ out)
{
    __shared__ float st[NSLOT * 4];        // 4 grouped-halo rows, 8704 B

    const int tid = threadIdx.x;
    const int qy  = blockIdx.x;
    const int b   = blockIdx.y;

    const int   ry = ry0[qy];              // uniform scalar load
    const float4 wy = wyw[qy];             // uniform scalar load

    // ---- stage 544 f4 slots via async DMA (2 full rounds + 32-slot tail)
    const float* sb = sig + (size_t)b * H_ * W_;
    #pragma unroll
    for (int it = 0; it < 2; ++it) {
        int j   = it * 256 + tid;          // < 512
        int s   = j / SLOTS_R;
        int k   = j - s * SLOTS_R;
        int g   = k / SLOT_G;
        int sub = k - g * SLOT_G;
        int gr  = min(ry + s, H_ - 1);     // row-clamp (ry <= 509; ry+3 may clip)
        int idx = min(16 * g + sub, 127);  // halo: next group's first 16B / clamp
        gload_lds16(sb + (size_t)gr * W_ + idx * 4, st + (size_t)j * 4);
    }
    if (tid < NSLOT - 512) {               // tail: 32 slots (lanes 0-31 of wave 0)
        int j   = 512 + tid;
        int s   = j / SLOTS_R;
        int k   = j - s * SLOTS_R;
        int g   = k / SLOT_G;
        int sub = k - g * SLOT_G;
        int gr  = min(ry + s, H_ - 1);
        int idx = min(16 * g + sub, 127);
        gload_lds16(sb + (size_t)gr * W_ + idx * 4, st + (size_t)j * 4);
    }

    // ---- per-thread x windows from tables (overlaps DMA)
    const int qxb = tid * 4;
    const float4 w0 = wxw[qxb], w1 = wxw[qxb + 1], w2 = wxw[qxb + 2], w3 = wxw[qxb + 3];
    const int4 bx = *(const int4*)(bx0 + qxb);

    __syncthreads();   // drains DMA (vmcnt) before LDS reads

    // ---- 4 rows x 4 qx col-interp + uniform y-combine
    float4 acc = make_float4(0.f, 0.f, 0.f, 0.f);
    const float wys[4] = {wy.x, wy.y, wy.z, wy.w};
    #pragma unroll
    for (int s = 0; s < NROWS; ++s) {
        const float* sr = st + s * SROW;
        float4 c;
        c.x = w0.x * sr[bx.x] + w0.y * sr[bx.x + 1] + w0.z * sr[bx.x + 2] + w0.w * sr[bx.x + 3];
        c.y = w1.x * sr[bx.y] + w1.y * sr[bx.y + 1] + w1.z * sr[bx.y + 2] + w1.w * sr[bx.y + 3];
        c.z = w2.x * sr[bx.z] + w2.y * sr[bx.z + 1] + w2.z * sr[bx.z + 2] + w2.w * sr[bx.z + 3];
        c.w = w3.x * sr[bx.w] + w3.y * sr[bx.w + 1] + w3.z * sr[bx.w + 2] + w3.w * sr[bx.w + 3];
        acc = f4fma(wys[s], c, acc);
    }

    // ---- one full-row cached f4 store (line-exclusive -> clean write-back)
    *(float4*)(out + (size_t)b * NY_ * NX_ + (size_t)qy * NX_ + qxb) = acc;
}

extern "C" void kernel_launch(void* const* d_in, const int* in_sizes, int n_in,
                              void* d_out, int out_size, void* d_ws, size_t ws_size,
                              hipStream_t stream) {
    const float* signal = (const float*)d_in[0];
    // d_in[1] = x1 (arange W), d_in[2] = x2 (arange H): dx=1, folded analytically
    const float* xs = (const float*)d_in[3];
    const float* ys = (const float*)d_in[4];
    float* out = (float*)d_out;

    // Workspace: wxw[NX] f4 | wyw[NY] f4 | bx0[NX] i | ry0[NY] i  (40 KB)
    float4* wxw = (float4*)d_ws;
    float4* wyw = wxw + NX_;
    int* bx0 = (int*)(wyw + NY_);
    int* ry0 = bx0 + NX_;

    prep_tables<<<(NX_ + NY_ + 255) / 256, 256, 0, stream>>>(
        xs, ys, wxw, bx0, wyw, ry0);

    dim3 grid(NY_, B_);    // 32768 row-blocks
    fused<<<grid, 256, 0, stream>>>(signal, wxw, bx0, wyw, ry0, out);
}

// Round 14
// 209.705 us; speedup vs baseline: 1.0011x; 1.0011x over previous
//
#include <hip/hip_runtime.h>

// Problem constants (fixed by setup_inputs)
#define B_  32
#define H_  512
#define W_  512
#define NX_ 1024
#define NY_ 1024

// Grouped-halo staged row: 8 groups x (64 data + 4 halo floats) = 544 floats.
// Window [c0,c0+3] contiguous at off = c0 + 4*(c0>>6) (precomputed in bx0).
// Linear in f4 slots (17/group) -> global_load_lds keeps a linear LDS dst;
// the halo lives in the per-lane SOURCE address (idx = min(16g+sub,127)).
#define SLOT_G  17
#define SLOTS_R 136          // f4 slots per staged row
#define SROW    544          // floats per staged row
#define NROWS   4            // rows staged per block (one y-window)
#define NSLOT   (NROWS * SLOTS_R)   // 544 slots = 8704 B

__device__ __forceinline__ float4 f4fma(float s, float4 a, float4 acc) {
    acc.x += s * a.x; acc.y += s * a.y; acc.z += s * a.z; acc.w += s * a.w;
    return acc;
}

__device__ __forceinline__ void gload_lds16(const float* g, float* l) {
    __builtin_amdgcn_global_load_lds(
        (const __attribute__((address_space(1))) void*)g,
        (__attribute__((address_space(3))) void*)l,
        16, 0, 0);
}

// Hermite basis + FD tangents folded into a contiguous 4-tap window
// [c0, c0+3]; boundary cases pre-shifted, out-of-range taps weight-0.
__device__ __forceinline__ void hermite_window(float x, int N, int& c0, float4& v) {
    int i = (int)floorf(x);
    i = min(max(i, 0), N - 2);
    float t  = x - (float)i;
    float t2 = t * t;
    float t3 = t2 * t;
    float h00 = 1.0f - 3.0f * t2 + 2.0f * t3;
    float h10 = t - 2.0f * t2 + t3;
    float h01 = 3.0f * t2 - 2.0f * t3;
    float h11 = t3 - t2;
    if (i == 0) {
        c0 = 0;
        v = make_float4(h00 - h10 - 0.5f * h11, h01 + h10, 0.5f * h11, 0.0f);
    } else if (i == N - 2) {
        c0 = i - 1;
        v = make_float4(-0.5f * h10, h00 - h11, h01 + 0.5f * h10 + h11, 0.0f);
    } else {
        c0 = i - 1;
        v = make_float4(-0.5f * h10, h00 - 0.5f * h11, h01 + 0.5f * h10, 0.5f * h11);
    }
}

// Precompute query tables: x windows (grouped-halo offset) + y windows (row).
__global__ void prep_tables(const float* __restrict__ xs, const float* __restrict__ ys,
                            float4* __restrict__ wxw, int* __restrict__ bx0,
                            float4* __restrict__ wyw, int* __restrict__ ry0) {
    int q = blockIdx.x * blockDim.x + threadIdx.x;
    if (q < NX_) {
        int c; float4 w;
        hermite_window(xs[q], W_, c, w);
        wxw[q] = w;
        bx0[q] = c + ((c >> 6) << 2);       // grouped-halo LDS offset
    } else if (q < NX_ + NY_) {
        int qq = q - NX_;
        int c; float4 w;
        hermite_window(ys[qq], H_, c, w);
        wyw[qq] = w;
        ry0[qq] = c;                        // first source row of the window
    }
}

// Row-per-block streaming stencil. One block = one output row (qy) x batch.
// XCD-chunked bijective swizzle: consecutive qy (sharing 3/4 source rows)
// run on the SAME XCD -> each source row is HBM-fetched by exactly one XCD
// and reused from its L2. (R13 measured the un-swizzled dispatch scattering
// neighbor rows across XCDs: FETCH 113 MB = 3.5x signal.)
__global__ __launch_bounds__(256) void fused(
    const float* __restrict__ sig,
    const float4* __restrict__ wxw, const int* __restrict__ bx0,
    const float4* __restrict__ wyw, const int* __restrict__ ry0,
    float* __restrict__ out)
{
    __shared__ float st[NSLOT * 4];        // 4 grouped-halo rows, 8704 B

    const int tid = threadIdx.x;
    // bijective XCD chunking (nwg = 32768, nwg % 8 == 0):
    // XCD x owns swz in [x*4096, (x+1)*4096) = batches 4x..4x+3, qy ascending.
    const int lin = blockIdx.x;
    const int swz = (lin & 7) * (B_ * NY_ / 8) + (lin >> 3);
    const int qy  = swz & (NY_ - 1);
    const int b   = swz >> 10;

    const int   ry = ry0[qy];              // uniform scalar load
    const float4 wy = wyw[qy];             // uniform scalar load

    // ---- stage 544 f4 slots via async DMA (2 full rounds + 32-slot tail)
    const float* sb = sig + (size_t)b * H_ * W_;
    #pragma unroll
    for (int it = 0; it < 2; ++it) {
        int j   = it * 256 + tid;          // < 512
        int s   = j / SLOTS_R;
        int k   = j - s * SLOTS_R;
        int g   = k / SLOT_G;
        int sub = k - g * SLOT_G;
        int gr  = min(ry + s, H_ - 1);     // row-clamp (ry <= 509; ry+3 may clip)
        int idx = min(16 * g + sub, 127);  // halo: next group's first 16B / clamp
        gload_lds16(sb + (size_t)gr * W_ + idx * 4, st + (size_t)j * 4);
    }
    if (tid < NSLOT - 512) {               // tail: 32 slots (lanes 0-31 of wave 0)
        int j   = 512 + tid;
        int s   = j / SLOTS_R;
        int k   = j - s * SLOTS_R;
        int g   = k / SLOT_G;
        int sub = k - g * SLOT_G;
        int gr  = min(ry + s, H_ - 1);
        int idx = min(16 * g + sub, 127);
        gload_lds16(sb + (size_t)gr * W_ + idx * 4, st + (size_t)j * 4);
    }

    // ---- per-thread x windows from tables (overlaps DMA)
    const int qxb = tid * 4;
    const float4 w0 = wxw[qxb], w1 = wxw[qxb + 1], w2 = wxw[qxb + 2], w3 = wxw[qxb + 3];
    const int4 bx = *(const int4*)(bx0 + qxb);

    __syncthreads();   // drains DMA (vmcnt) before LDS reads

    // ---- 4 rows x 4 qx col-interp + uniform y-combine
    float4 acc = make_float4(0.f, 0.f, 0.f, 0.f);
    const float wys[4] = {wy.x, wy.y, wy.z, wy.w};
    #pragma unroll
    for (int s = 0; s < NROWS; ++s) {
        const float* sr = st + s * SROW;
        float4 c;
        c.x = w0.x * sr[bx.x] + w0.y * sr[bx.x + 1] + w0.z * sr[bx.x + 2] + w0.w * sr[bx.x + 3];
        c.y = w1.x * sr[bx.y] + w1.y * sr[bx.y + 1] + w1.z * sr[bx.y + 2] + w1.w * sr[bx.y + 3];
        c.z = w2.x * sr[bx.z] + w2.y * sr[bx.z + 1] + w2.z * sr[bx.z + 2] + w2.w * sr[bx.z + 3];
        c.w = w3.x * sr[bx.w] + w3.y * sr[bx.w + 1] + w3.z * sr[bx.w + 2] + w3.w * sr[bx.w + 3];
        acc = f4fma(wys[s], c, acc);
    }

    // ---- one full-row cached f4 store (line-exclusive -> clean write-back)
    *(float4*)(out + (size_t)b * NY_ * NX_ + (size_t)qy * NX_ + qxb) = acc;
}

extern "C" void kernel_launch(void* const* d_in, const int* in_sizes, int n_in,
                              void* d_out, int out_size, void* d_ws, size_t ws_size,
                              hipStream_t stream) {
    const float* signal = (const float*)d_in[0];
    // d_in[1] = x1 (arange W), d_in[2] = x2 (arange H): dx=1, folded analytically
    const float* xs = (const float*)d_in[3];
    const float* ys = (const float*)d_in[4];
    float* out = (float*)d_out;

    // Workspace: wxw[NX] f4 | wyw[NY] f4 | bx0[NX] i | ry0[NY] i  (40 KB)
    float4* wxw = (float4*)d_ws;
    float4* wyw = wxw + NX_;
    int* bx0 = (int*)(wyw + NY_);
    int* ry0 = bx0 + NX_;

    prep_tables<<<(NX_ + NY_ + 255) / 256, 256, 0, stream>>>(
        xs, ys, wxw, bx0, wyw, ry0);

    fused<<<dim3(B_ * NY_), 256, 0, stream>>>(signal, wxw, bx0, wyw, ry0, out);
}